// Round 3
// baseline (199.567 us; speedup 1.0000x reference)
//
#include <hip/hip_runtime.h>
#include <hip/hip_bf16.h>

#define SEQ 2048
#define H_ 8
#define D_ 32
#define SPLIT 4
#define KCHUNK 512  // SEQ / SPLIT

typedef __attribute__((ext_vector_type(4))) short short4v;
typedef __attribute__((ext_vector_type(8))) short short8v;
typedef __attribute__((ext_vector_type(4))) float floatx4;

static __device__ __forceinline__ unsigned short f2bf(float f) {
  union { float f; unsigned u; } v; v.f = f;
  unsigned r = v.u + 0x7fff + ((v.u >> 16) & 1);
  return (unsigned short)(r >> 16);
}
static __device__ __forceinline__ float bf2f(unsigned short h) {
  union { unsigned u; float f; } v; v.u = ((unsigned)h) << 16; return v.f;
}
// fragment permutation within a 32-elem k-block: actual k -> stored pos
static __device__ __forceinline__ int pd(int d) {
  return ((d & 12) << 1) | (d & 3) | ((d & 16) >> 2);
}

// ---------- prep: weights -> bf16 (k-permuted), qx/kvx -> bf16 (k-permuted) ---
__global__ __launch_bounds__(256) void prep_all(
    const float* wq, const float* wk, const float* wv, const float* wg,
    const float* wo, const float* qx, const float* kvx,
    unsigned short* wbf, unsigned short* xqb, unsigned short* xkb) {
  if (blockIdx.x < 1280) {
    int i = blockIdx.x * 256 + threadIdx.x;  // [0, 5*65536)
    int m = i >> 16, j = i & 65535;
    int n = j >> 8, k = j & 255;
    const float* s = (m == 0) ? wq : (m == 1) ? wk : (m == 2) ? wv : (m == 3) ? wg : wo;
    wbf[(m << 16) + n * 256 + ((k & ~31) | pd(k & 31))] = f2bf(s[j]);
  } else {
    int i = (blockIdx.x - 1280) * 256 + threadIdx.x;  // [0, 524288) quads
    int m = i >> 18;
    int j = (i & 262143) * 4;
    const float* X = m ? kvx : qx;
    unsigned short* O = m ? xkb : xqb;
    floatx4 f = *(const floatx4*)(X + j);
    int row = j >> 8, k = j & 255;
    int base = row * 256 + (k & ~31) + ((k & 12) << 1) + ((k & 16) >> 2);
    short4v s;
#pragma unroll
    for (int r = 0; r < 4; ++r) s[r] = (short)f2bf(f[r]);
    *(short4v*)(O + base) = s;
  }
}

// ---------- QKVG projections: register-held W panel, no LDS, no barriers -----
// wave = (sel, nchunk of 16 cols, mgroup of 64 rows); 4 m-tiles of 16 rows.
// sel 0: xqb x Wq -> qp (scaled, permuted)   sel 1: xqb x Wg -> gate (sigmoid)
// sel 2: xkb x Wk -> kp (permuted)           sel 3: xkb x Wv -> vt (s-permuted)
__global__ __launch_bounds__(256) void proj_qkvg(
    const unsigned short* xqb, const unsigned short* xkb,
    const unsigned short* wbf, unsigned short* qp, unsigned short* kp,
    unsigned short* vt, unsigned short* gate, const float* bg) {
  const int gw = blockIdx.x * 4 + (threadIdx.x >> 6);
  const int lane = threadIdx.x & 63;
  const int g = lane >> 4, l15 = lane & 15;
  const int sel = gw >> 10;
  const int nchunk = (gw >> 6) & 15;
  const int mgroup = gw & 63;
  const unsigned short* xb = (sel < 2) ? xqb : xkb;
  const unsigned short* wsel =
      wbf + ((sel == 0) ? 0 : (sel == 1) ? 3 : (sel == 2) ? 1 : 2) * 65536;
  const int n = nchunk * 16 + l15;

  short8v w[8];
#pragma unroll
  for (int ks = 0; ks < 8; ++ks)
    w[ks] = *(const short8v*)(wsel + n * 256 + ks * 32 + 8 * g);

#pragma unroll
  for (int mt = 0; mt < 4; ++mt) {
    int row0 = mgroup * 64 + mt * 16;
    floatx4 acc = {0.f, 0.f, 0.f, 0.f};
#pragma unroll
    for (int ks = 0; ks < 8; ++ks) {
      short8v A = *(const short8v*)(xb + (row0 + l15) * 256 + ks * 32 + 8 * g);
      acc = __builtin_amdgcn_mfma_f32_16x16x32_bf16(A, w[ks], acc, 0, 0, 0);
    }
    int b = row0 >> 11, s = row0 & 2047;
    if (sel == 0) {
      int h = n >> 5, d = n & 31;
      unsigned short* dst = qp + ((b * H_ + h) * SEQ + s + 4 * g) * D_ + pd(d);
#pragma unroll
      for (int r = 0; r < 4; ++r)
        dst[r * D_] = f2bf(acc[r] * 0.17677669529663687f);
    } else if (sel == 1) {
      float bgn = bg[n];
#pragma unroll
      for (int r = 0; r < 4; ++r) {
        float sg = 1.f / (1.f + __expf(-(acc[r] + bgn)));
        gate[(b * SEQ + s + 4 * g + r) * 256 + n] = f2bf(sg);
      }
    } else if (sel == 2) {
      int h = n >> 5, d = n & 31;
      unsigned short* dst = kp + ((b * H_ + h) * SEQ + s + 4 * g) * D_ + pd(d);
#pragma unroll
      for (int r = 0; r < 4; ++r)
        dst[r * D_] = f2bf(acc[r]);
    } else {
      int h = n >> 5, d = n & 31;
      int sb = (s & ~31) + 8 * g + ((row0 & 16) ? 4 : 0);
      short4v vv;
#pragma unroll
      for (int r = 0; r < 4; ++r) vv[r] = (short)f2bf(acc[r]);
      *(short4v*)(vt + ((b * H_ + h) * D_ + d) * SEQ + sb) = vv;
    }
  }
}

// ---------- attention, split-k: wave = (head, q-tile); block z = k-chunk -----
__global__ __launch_bounds__(512) void attn_kernel(
    const unsigned short* qp, const unsigned short* kp, const unsigned short* vt,
    const float* bias, float* po, float* pl) {
  const int tid = threadIdx.x;
  const int lane = tid & 63;
  const int h = tid >> 6;
  const int b = blockIdx.y;
  const int qt = blockIdx.x;
  const int chunk = blockIdx.z;
  const int q0 = qt * 16;
  const int g = lane >> 4, l15 = lane & 15;

  short8v qfrag = *(const short8v*)(qp + ((b * H_ + h) * SEQ + q0 + l15) * D_ + 8 * g);
  const unsigned short* kpb = kp + (b * H_ + h) * SEQ * D_;
  const unsigned short* vtb = vt + (b * H_ + h) * D_ * SEQ;
  const float* biasb = bias + (b * SEQ + q0 + l15) * SEQ;

  floatx4 o0 = {0.f, 0.f, 0.f, 0.f}, o1 = {0.f, 0.f, 0.f, 0.f};
  float lacc = 0.f;

  const int kbeg = chunk * KCHUNK;
#pragma unroll 2
  for (int k0 = kbeg; k0 < kbeg + KCHUNK; k0 += 32) {
    short8v kf0 = *(const short8v*)(kpb + (k0 + l15) * D_ + 8 * g);
    short8v kf1 = *(const short8v*)(kpb + (k0 + 16 + l15) * D_ + 8 * g);
    floatx4 z = {0.f, 0.f, 0.f, 0.f};
    floatx4 s0 = __builtin_amdgcn_mfma_f32_16x16x32_bf16(kf0, qfrag, z, 0, 0, 0);
    floatx4 s1 = __builtin_amdgcn_mfma_f32_16x16x32_bf16(kf1, qfrag, z, 0, 0, 0);
    floatx4 bv0 = *(const floatx4*)(biasb + k0 + 4 * g);
    floatx4 bv1 = *(const floatx4*)(biasb + k0 + 16 + 4 * g);
    short8v pf;
#pragma unroll
    for (int r = 0; r < 4; ++r) {
      float p0 = __expf(s0[r] + bv0[r]);
      float p1 = __expf(s1[r] + bv1[r]);
      lacc += p0 + p1;
      pf[r] = (short)f2bf(p0);
      pf[4 + r] = (short)f2bf(p1);
    }
    short8v vf0 = *(const short8v*)(vtb + l15 * SEQ + k0 + 8 * g);
    short8v vf1 = *(const short8v*)(vtb + (16 + l15) * SEQ + k0 + 8 * g);
    o0 = __builtin_amdgcn_mfma_f32_16x16x32_bf16(vf0, pf, o0, 0, 0, 0);
    o1 = __builtin_amdgcn_mfma_f32_16x16x32_bf16(vf1, pf, o1, 0, 0, 0);
  }

  lacc += __shfl_xor(lacc, 16, 64);
  lacc += __shfl_xor(lacc, 32, 64);

  const int widg = ((chunk * 2 + b) * H_ + h) * 128 + qt;
  float* pob = po + (size_t)widg * 512;
  *(floatx4*)(pob + lane * 8) = o0;
  *(floatx4*)(pob + lane * 8 + 4) = o1;
  if (lane < 16) pl[widg * 16 + l15] = lacc;
}

// ---------- reduce: sum chunks, normalize, gate, write ao (permuted) ---------
__global__ __launch_bounds__(512) void reduce_kernel(
    const float* po, const float* pl, const unsigned short* gate,
    unsigned short* ao) {
  const int bh = blockIdx.x;  // ((b*8+h)*128 + qt)
  const int qt = bh & 127;
  const int h = (bh >> 7) & 7;
  const int b = bh >> 10;
  const int j = threadIdx.x;  // 0..511
  const int lane_s = j >> 3, e = j & 7;
  const int q = lane_s & 15;

  float o = 0.f, l = 0.f;
#pragma unroll
  for (int c = 0; c < SPLIT; ++c) {
    int widg = ((c * 2 + b) * H_ + h) * 128 + qt;
    o += po[(size_t)widg * 512 + j];
    l += pl[widg * 16 + q];
  }
  int dt = e >> 2, r = e & 3, g = lane_s >> 4;
  int d = dt * 16 + 4 * g + r;
  int s = qt * 16 + q;
  float gv = bf2f(gate[(b * SEQ + s) * 256 + h * D_ + d]);
  ao[(b * SEQ + s) * 256 + h * D_ + pd(d)] = f2bf(o / l * gv);
}

// ---------- output projection: register W, A = permuted ao ------------------
__global__ __launch_bounds__(256) void proj_out(
    const unsigned short* ao, const unsigned short* wbf, float* outp,
    const float* bo) {
  const int gw = blockIdx.x * 4 + (threadIdx.x >> 6);
  const int lane = threadIdx.x & 63;
  const int g = lane >> 4, l15 = lane & 15;
  const int nchunk = gw >> 6;
  const int mgroup = gw & 63;
  const unsigned short* wsel = wbf + 4 * 65536;
  const int n = nchunk * 16 + l15;

  short8v w[8];
#pragma unroll
  for (int ks = 0; ks < 8; ++ks)
    w[ks] = *(const short8v*)(wsel + n * 256 + ks * 32 + 8 * g);
  float bon = bo[n];

#pragma unroll
  for (int mt = 0; mt < 4; ++mt) {
    int row0 = mgroup * 64 + mt * 16;
    floatx4 acc = {0.f, 0.f, 0.f, 0.f};
#pragma unroll
    for (int ks = 0; ks < 8; ++ks) {
      short8v A = *(const short8v*)(ao + (row0 + l15) * 256 + ks * 32 + 8 * g);
      acc = __builtin_amdgcn_mfma_f32_16x16x32_bf16(A, w[ks], acc, 0, 0, 0);
    }
#pragma unroll
    for (int r = 0; r < 4; ++r)
      outp[(row0 + 4 * g + r) * 256 + n] = acc[r] + bon;
  }
}

extern "C" void kernel_launch(void* const* d_in, const int* in_sizes, int n_in,
                              void* d_out, int out_size, void* d_ws, size_t ws_size,
                              hipStream_t stream) {
  const float* qx = (const float*)d_in[0];
  const float* kvx = (const float*)d_in[1];
  const float* bias = (const float*)d_in[2];
  const float* Wq = (const float*)d_in[3];
  const float* Wk = (const float*)d_in[4];
  const float* Wv = (const float*)d_in[5];
  const float* Wo = (const float*)d_in[6];
  const float* bo = (const float*)d_in[7];
  const float* Wg = (const float*)d_in[8];
  const float* bg = (const float*)d_in[9];
  float* out = (float*)d_out;

  unsigned short* ws = (unsigned short*)d_ws;
  unsigned short* wbf = ws;                  // 5*65536
  unsigned short* xqb = ws + 327680;         // [4096][256] bf16 permuted
  unsigned short* xkb = xqb + 1048576;
  unsigned short* qp = xkb + 1048576;        // [2][8][2048][32] d-permuted
  unsigned short* kp = qp + 1048576;
  unsigned short* vt = kp + 1048576;         // [2][8][32][2048] s-permuted
  unsigned short* gate = vt + 1048576;       // [2][2048][256]
  unsigned short* ao = gate + 1048576;       // [2][2048][256] k-permuted
  float* po = (float*)(ao + 1048576);        // [SPLIT*2*8*128][512]
  float* pl = po + (size_t)SPLIT * 2 * H_ * 128 * 512;  // [...][16]

  prep_all<<<dim3(3328), dim3(256), 0, stream>>>(Wq, Wk, Wv, Wg, Wo, qx, kvx,
                                                 wbf, xqb, xkb);
  proj_qkvg<<<dim3(1024), dim3(256), 0, stream>>>(xqb, xkb, wbf, qp, kp, vt,
                                                  gate, bg);
  attn_kernel<<<dim3(128, 2, SPLIT), dim3(512), 0, stream>>>(qp, kp, vt, bias,
                                                             po, pl);
  reduce_kernel<<<dim3(2048), dim3(512), 0, stream>>>(po, pl, gate, ao);
  proj_out<<<dim3(256), dim3(256), 0, stream>>>(ao, wbf, out, bo);
}

// Round 5
// 198.524 us; speedup vs baseline: 1.0053x; 1.0053x over previous
//
#include <hip/hip_runtime.h>
#include <hip/hip_bf16.h>

#define SEQ 2048
#define H_ 8
#define D_ 32
#define SPLIT 4
#define KCHUNK 512  // SEQ / SPLIT

typedef __attribute__((ext_vector_type(4))) short short4v;
typedef __attribute__((ext_vector_type(8))) short short8v;
typedef __attribute__((ext_vector_type(4))) float floatx4;

static __device__ __forceinline__ unsigned short f2bf(float f) {
  union { float f; unsigned u; } v; v.f = f;
  unsigned r = v.u + 0x7fff + ((v.u >> 16) & 1);
  return (unsigned short)(r >> 16);
}
static __device__ __forceinline__ float bf2f(unsigned short h) {
  union { unsigned u; float f; } v; v.u = ((unsigned)h) << 16; return v.f;
}
// fragment permutation within a 32-elem k-block: actual k -> stored pos
static __device__ __forceinline__ int pd(int d) {
  return ((d & 12) << 1) | (d & 3) | ((d & 16) >> 2);
}

// ---------- prep: weights -> bf16 (k-permuted), qx/kvx -> bf16 (k-permuted) ---
__global__ __launch_bounds__(256) void prep_all(
    const float* wq, const float* wk, const float* wv, const float* wg,
    const float* wo, const float* qx, const float* kvx,
    unsigned short* wbf, unsigned short* xqb, unsigned short* xkb) {
  if (blockIdx.x < 1280) {
    int i = blockIdx.x * 256 + threadIdx.x;  // [0, 5*65536)
    int m = i >> 16, j = i & 65535;
    int n = j >> 8, k = j & 255;
    const float* s = (m == 0) ? wq : (m == 1) ? wk : (m == 2) ? wv : (m == 3) ? wg : wo;
    wbf[(m << 16) + n * 256 + ((k & ~31) | pd(k & 31))] = f2bf(s[j]);
  } else {
    int i = (blockIdx.x - 1280) * 256 + threadIdx.x;  // [0, 524288) quads
    int m = i >> 18;
    int j = (i & 262143) * 4;
    const float* X = m ? kvx : qx;
    unsigned short* O = m ? xkb : xqb;
    floatx4 f = *(const floatx4*)(X + j);
    int row = j >> 8, k = j & 255;
    int base = row * 256 + (k & ~31) + ((k & 12) << 1) + ((k & 16) >> 2);
    short4v s;
#pragma unroll
    for (int r = 0; r < 4; ++r) s[r] = (short)f2bf(f[r]);
    *(short4v*)(O + base) = s;
  }
}

// ---------- QKVG projections: register W panel, prefetched A, no LDS ---------
__global__ __launch_bounds__(256) void proj_qkvg(
    const unsigned short* xqb, const unsigned short* xkb,
    const unsigned short* wbf, unsigned short* qp, unsigned short* kp,
    unsigned short* vt, unsigned short* gate, const float* bg) {
  const int gw = blockIdx.x * 4 + (threadIdx.x >> 6);
  const int lane = threadIdx.x & 63;
  const int g = lane >> 4, l15 = lane & 15;
  const int sel = gw >> 10;
  const int nchunk = (gw >> 6) & 15;
  const int mgroup = gw & 63;
  const unsigned short* xb = (sel < 2) ? xqb : xkb;
  const unsigned short* wsel =
      wbf + ((sel == 0) ? 0 : (sel == 1) ? 3 : (sel == 2) ? 1 : 2) * 65536;
  const int n = nchunk * 16 + l15;

  short8v w[8];
#pragma unroll
  for (int ks = 0; ks < 8; ++ks)
    w[ks] = *(const short8v*)(wsel + n * 256 + ks * 32 + 8 * g);

  short8v a[8], an[8];
#pragma unroll
  for (int ks = 0; ks < 8; ++ks)
    a[ks] = *(const short8v*)(xb + (mgroup * 64 + l15) * 256 + ks * 32 + 8 * g);

#pragma unroll
  for (int mt = 0; mt < 4; ++mt) {
    int rown = mgroup * 64 + ((mt + 1) & 3) * 16;
#pragma unroll
    for (int ks = 0; ks < 8; ++ks)
      an[ks] = *(const short8v*)(xb + (rown + l15) * 256 + ks * 32 + 8 * g);

    floatx4 acc = {0.f, 0.f, 0.f, 0.f};
#pragma unroll
    for (int ks = 0; ks < 8; ++ks)
      acc = __builtin_amdgcn_mfma_f32_16x16x32_bf16(a[ks], w[ks], acc, 0, 0, 0);

    int row0 = mgroup * 64 + mt * 16;
    int b = row0 >> 11, s = row0 & 2047;
    if (sel == 0) {
      int h = n >> 5, d = n & 31;
      unsigned short* dst = qp + ((b * H_ + h) * SEQ + s + 4 * g) * D_ + pd(d);
#pragma unroll
      for (int r = 0; r < 4; ++r)
        dst[r * D_] = f2bf(acc[r] * 0.17677669529663687f);
    } else if (sel == 1) {
      float bgn = bg[n];
#pragma unroll
      for (int r = 0; r < 4; ++r) {
        float sg = 1.f / (1.f + __expf(-(acc[r] + bgn)));
        gate[(b * SEQ + s + 4 * g + r) * 256 + n] = f2bf(sg);
      }
    } else if (sel == 2) {
      int h = n >> 5, d = n & 31;
      unsigned short* dst = kp + ((b * H_ + h) * SEQ + s + 4 * g) * D_ + pd(d);
#pragma unroll
      for (int r = 0; r < 4; ++r)
        dst[r * D_] = f2bf(acc[r]);
    } else {
      int h = n >> 5, d = n & 31;
      int sb = (s & ~31) + 8 * g + ((row0 & 16) ? 4 : 0);
      short4v vv;
#pragma unroll
      for (int r = 0; r < 4; ++r) vv[r] = (short)f2bf(acc[r]);
      *(short4v*)(vt + ((b * H_ + h) * D_ + d) * SEQ + sb) = vv;
    }
#pragma unroll
    for (int ks = 0; ks < 8; ++ks) a[ks] = an[ks];
  }
}

// ---------- attention, split-k, depth-2 software pipeline --------------------
__global__ __launch_bounds__(512) void attn_kernel(
    const unsigned short* qp, const unsigned short* kp, const unsigned short* vt,
    const float* bias, float* po, float* pl) {
  const int tid = threadIdx.x;
  const int lane = tid & 63;
  const int h = tid >> 6;
  const int b = blockIdx.y;
  const int qt = blockIdx.x;
  const int chunk = blockIdx.z;
  const int q0 = qt * 16;
  const int g = lane >> 4, l15 = lane & 15;

  short8v qfrag = *(const short8v*)(qp + ((b * H_ + h) * SEQ + q0 + l15) * D_ + 8 * g);
  const unsigned short* kpb = kp + (b * H_ + h) * SEQ * D_;
  const unsigned short* vtb = vt + (b * H_ + h) * D_ * SEQ;
  const float* biasb = bias + (b * SEQ + q0 + l15) * SEQ;

  floatx4 o0 = {0.f, 0.f, 0.f, 0.f}, o1 = {0.f, 0.f, 0.f, 0.f};
  float lacc = 0.f;

  const int kbeg = chunk * KCHUNK;
  const int kend = kbeg + KCHUNK;

  // prologue loads (iteration 0)
  short8v kc0 = *(const short8v*)(kpb + (kbeg + l15) * D_ + 8 * g);
  short8v kc1 = *(const short8v*)(kpb + (kbeg + 16 + l15) * D_ + 8 * g);
  short8v vc0 = *(const short8v*)(vtb + l15 * SEQ + kbeg + 8 * g);
  short8v vc1 = *(const short8v*)(vtb + (16 + l15) * SEQ + kbeg + 8 * g);
  floatx4 bc0 = *(const floatx4*)(biasb + kbeg + 4 * g);
  floatx4 bc1 = *(const floatx4*)(biasb + kbeg + 16 + 4 * g);

  for (int k0 = kbeg; k0 < kend; k0 += 32) {
    // issue next-iteration loads (wrap to kbeg on last iter; result unused)
    int kn = (k0 + 32 < kend) ? k0 + 32 : kbeg;
    short8v kn0 = *(const short8v*)(kpb + (kn + l15) * D_ + 8 * g);
    short8v kn1 = *(const short8v*)(kpb + (kn + 16 + l15) * D_ + 8 * g);
    short8v vn0 = *(const short8v*)(vtb + l15 * SEQ + kn + 8 * g);
    short8v vn1 = *(const short8v*)(vtb + (16 + l15) * SEQ + kn + 8 * g);
    floatx4 bn0 = *(const floatx4*)(biasb + kn + 4 * g);
    floatx4 bn1 = *(const floatx4*)(biasb + kn + 16 + 4 * g);

    // compute with current registers
    floatx4 z = {0.f, 0.f, 0.f, 0.f};
    floatx4 s0 = __builtin_amdgcn_mfma_f32_16x16x32_bf16(kc0, qfrag, z, 0, 0, 0);
    floatx4 s1 = __builtin_amdgcn_mfma_f32_16x16x32_bf16(kc1, qfrag, z, 0, 0, 0);
    short8v pf;
#pragma unroll
    for (int r = 0; r < 4; ++r) {
      float p0 = __expf(s0[r] + bc0[r]);
      float p1 = __expf(s1[r] + bc1[r]);
      lacc += p0 + p1;
      pf[r] = (short)f2bf(p0);
      pf[4 + r] = (short)f2bf(p1);
    }
    o0 = __builtin_amdgcn_mfma_f32_16x16x32_bf16(vc0, pf, o0, 0, 0, 0);
    o1 = __builtin_amdgcn_mfma_f32_16x16x32_bf16(vc1, pf, o1, 0, 0, 0);

    kc0 = kn0; kc1 = kn1; vc0 = vn0; vc1 = vn1; bc0 = bn0; bc1 = bn1;
  }

  lacc += __shfl_xor(lacc, 16, 64);
  lacc += __shfl_xor(lacc, 32, 64);

  const int widg = ((chunk * 2 + b) * H_ + h) * 128 + qt;
  float* pob = po + (size_t)widg * 512;
  *(floatx4*)(pob + lane * 8) = o0;
  *(floatx4*)(pob + lane * 8 + 4) = o1;
  if (lane < 16) pl[widg * 16 + l15] = lacc;
}

// ---------- reduce: sum chunks, normalize, gate, write ao (permuted) ---------
__global__ __launch_bounds__(512) void reduce_kernel(
    const float* po, const float* pl, const unsigned short* gate,
    unsigned short* ao) {
  const int bh = blockIdx.x;  // ((b*8+h)*128 + qt)
  const int qt = bh & 127;
  const int h = (bh >> 7) & 7;
  const int b = bh >> 10;
  const int j = threadIdx.x;  // 0..511
  const int lane_s = j >> 3, e = j & 7;
  const int q = lane_s & 15;

  float o = 0.f, l = 0.f;
#pragma unroll
  for (int c = 0; c < SPLIT; ++c) {
    int widg = ((c * 2 + b) * H_ + h) * 128 + qt;
    o += po[(size_t)widg * 512 + j];
    l += pl[widg * 16 + q];
  }
  int dt = e >> 2, r = e & 3, g = lane_s >> 4;
  int d = dt * 16 + 4 * g + r;
  int s = qt * 16 + q;
  float gv = bf2f(gate[(b * SEQ + s) * 256 + h * D_ + d]);
  ao[(b * SEQ + s) * 256 + h * D_ + pd(d)] = f2bf(o / l * gv);
}

// ---------- output projection: register W, prefetched A ---------------------
__global__ __launch_bounds__(256) void proj_out(
    const unsigned short* ao, const unsigned short* wbf, float* outp,
    const float* bo) {
  const int gw = blockIdx.x * 4 + (threadIdx.x >> 6);
  const int lane = threadIdx.x & 63;
  const int g = lane >> 4, l15 = lane & 15;
  const int nchunk = gw >> 6;
  const int mgroup = gw & 63;
  const unsigned short* wsel = wbf + 4 * 65536;
  const int n = nchunk * 16 + l15;

  short8v w[8];
#pragma unroll
  for (int ks = 0; ks < 8; ++ks)
    w[ks] = *(const short8v*)(wsel + n * 256 + ks * 32 + 8 * g);
  float bon = bo[n];

  short8v a[8], an[8];
#pragma unroll
  for (int ks = 0; ks < 8; ++ks)
    a[ks] = *(const short8v*)(ao + (mgroup * 64 + l15) * 256 + ks * 32 + 8 * g);

#pragma unroll
  for (int mt = 0; mt < 4; ++mt) {
    int rown = mgroup * 64 + ((mt + 1) & 3) * 16;
#pragma unroll
    for (int ks = 0; ks < 8; ++ks)
      an[ks] = *(const short8v*)(ao + (rown + l15) * 256 + ks * 32 + 8 * g);

    floatx4 acc = {0.f, 0.f, 0.f, 0.f};
#pragma unroll
    for (int ks = 0; ks < 8; ++ks)
      acc = __builtin_amdgcn_mfma_f32_16x16x32_bf16(a[ks], w[ks], acc, 0, 0, 0);

    int row0 = mgroup * 64 + mt * 16;
#pragma unroll
    for (int r = 0; r < 4; ++r)
      outp[(row0 + 4 * g + r) * 256 + n] = acc[r] + bon;

#pragma unroll
    for (int ks = 0; ks < 8; ++ks) a[ks] = an[ks];
  }
}

extern "C" void kernel_launch(void* const* d_in, const int* in_sizes, int n_in,
                              void* d_out, int out_size, void* d_ws, size_t ws_size,
                              hipStream_t stream) {
  const float* qx = (const float*)d_in[0];
  const float* kvx = (const float*)d_in[1];
  const float* bias = (const float*)d_in[2];
  const float* Wq = (const float*)d_in[3];
  const float* Wk = (const float*)d_in[4];
  const float* Wv = (const float*)d_in[5];
  const float* Wo = (const float*)d_in[6];
  const float* bo = (const float*)d_in[7];
  const float* Wg = (const float*)d_in[8];
  const float* bg = (const float*)d_in[9];
  float* out = (float*)d_out;

  unsigned short* ws = (unsigned short*)d_ws;
  unsigned short* wbf = ws;                  // 5*65536
  unsigned short* xqb = ws + 327680;         // [4096][256] bf16 permuted
  unsigned short* xkb = xqb + 1048576;
  unsigned short* qp = xkb + 1048576;        // [2][8][2048][32] d-permuted
  unsigned short* kp = qp + 1048576;
  unsigned short* vt = kp + 1048576;         // [2][8][32][2048] s-permuted
  unsigned short* gate = vt + 1048576;       // [2][2048][256]
  unsigned short* ao = gate + 1048576;       // [2][2048][256] k-permuted
  float* po = (float*)(ao + 1048576);        // [SPLIT*2*8*128][512]
  float* pl = po + (size_t)SPLIT * 2 * H_ * 128 * 512;  // [...][16]

  prep_all<<<dim3(3328), dim3(256), 0, stream>>>(Wq, Wk, Wv, Wg, Wo, qx, kvx,
                                                 wbf, xqb, xkb);
  proj_qkvg<<<dim3(1024), dim3(256), 0, stream>>>(xqb, xkb, wbf, qp, kp, vt,
                                                  gate, bg);
  attn_kernel<<<dim3(128, 2, SPLIT), dim3(512), 0, stream>>>(qp, kp, vt, bias,
                                                             po, pl);
  reduce_kernel<<<dim3(2048), dim3(512), 0, stream>>>(po, pl, gate, ao);
  proj_out<<<dim3(256), dim3(256), 0, stream>>>(ao, wbf, out, bo);
}